// Round 1
// baseline (293.506 us; speedup 1.0000x reference)
//
#include <hip/hip_runtime.h>

#define WIDTH   640
#define HEIGHT  384
#define PLANE   (WIDTH*HEIGHT)
#define STRIP_H 24
#define NSTRIP  16                /* 384/24 */
#define GROUPS  12                /* STRIP_H/2 */
#define NBLK    (96*NSTRIP)       /* 1536 = 6 blocks/CU exactly */
#define CS_W    656               /* slots 0..649 used, slot = x+5 */
#define SSIM_C1 1.0e-4f
#define SSIM_C2 9.0e-4f
#define INV_N   (1.0f/23592960.0f)

__global__ __launch_bounds__(256, 6)
void ssim_main(const float* __restrict__ pred, const float* __restrict__ targ,
               float* __restrict__ ws)
{
    // No raw-value ring anymore: the row leaving the 11-row window is re-read
    // from global (L2/L3-warm, exact same float -> exact cancellation in the
    // rolling sums). LDS = 21 KB -> 6 blocks/CU resident (grid-limited).
    __shared__ float4  cs[2][CS_W];       // column sums (Sp, St, Spp+Stt, Spt)
    __shared__ float   red[4];

    const int tid   = threadIdx.x;
    const int plane = blockIdx.x % 96;      // vertical neighbors differ by 96 -> same XCD
    const int strip = blockIdx.x / 96;      // 0..15
    const int y0s   = strip * STRIP_H;
    const float* __restrict__ P = pred + plane * PLANE;
    const float* __restrict__ T = targ + plane * PLANE;

    // zero horizontal-halo cs slots once (first Phase-B read is after the
    // first barrier, which orders this write)
    if (tid < 20) {
        int k = tid / 10, j = tid % 10;
        int s = (j < 5) ? j : (640 + j);    // {0..4, 645..649}
        cs[k][s] = make_float4(0.f, 0.f, 0.f, 0.f);
    }

    // ---- Bootstrap: column sums over rows [y0s-6, y0s+4] (window of output
    //      row y0s-1), all fp32, straight from global
    float S[3][4];
#pragma unroll
    for (int c = 0; c < 3; ++c) { S[c][0]=S[c][1]=S[c][2]=S[c][3]=0.f; }

#pragma unroll
    for (int c = 0; c < 3; ++c) {
        int x = tid + (c << 8);
        if (x < WIDTH) {
            for (int j = 0; j < 11; ++j) {
                int yy = y0s - 6 + j;
                float p = 0.f, t = 0.f;
                if (yy >= 0) { p = P[yy*WIDTH + x]; t = T[yy*WIDTH + x]; }
                S[c][0] += p;  S[c][1] += t;
                S[c][2] += p*p + t*t;
                S[c][3] += p*t;
            }
        }
    }

    // prefetch registers for the two rows entering the window each group
    // (fresh HBM reads -> long latency, worth explicit prefetch; leaving rows
    // are L2-warm and loaded directly in Phase A)
    float pfP[3][2], pfT[3][2];
    auto do_prefetch = [&](int gg) {
        const int y0 = y0s + (gg << 1);
#pragma unroll
        for (int c = 0; c < 3; ++c) {
            int x = tid + (c << 8);
            if (x < WIDTH) {
#pragma unroll
                for (int k = 0; k < 2; ++k) {
                    int yn = y0 + k + 5;
                    bool v = (yn < HEIGHT);
                    pfP[c][k] = v ? P[yn*WIDTH + x] : 0.f;
                    pfT[c][k] = v ? T[yn*WIDTH + x] : 0.f;
                }
            }
        }
    };
    do_prefetch(0);

    float acc = 0.f;
    const float inv121 = 1.0f / 121.0f;

    for (int g = 0; g < GROUPS; ++g) {
        // consume this group's prefetched rows, then immediately issue next
        // group's loads -> VMEM latency overlaps rest of A + barrier + B
        float cP[3][2], cT[3][2];
#pragma unroll
        for (int c = 0; c < 3; ++c)
#pragma unroll
            for (int k = 0; k < 2; ++k) { cP[c][k] = pfP[c][k]; cT[c][k] = pfT[c][k]; }

        if (g + 1 < GROUPS) do_prefetch(g + 1);

        const int y0 = y0s + (g << 1);

        // leaving rows: re-read from global (same float added 11 rows ago ->
        // exact cancellation). Issue all 12 loads before the arithmetic.
        float oP[3][2], oT[3][2];
#pragma unroll
        for (int c = 0; c < 3; ++c) {
            int x = tid + (c << 8);
            if (x < WIDTH) {
#pragma unroll
                for (int k = 0; k < 2; ++k) {
                    int yo = y0 + k - 6;
                    bool v = (yo >= 0);
                    oP[c][k] = v ? P[yo*WIDTH + x] : 0.f;
                    oT[c][k] = v ? T[yo*WIDTH + x] : 0.f;
                }
            }
        }

        // ---- Phase A: advance 2 rows (add entering, subtract leaving)
#pragma unroll
        for (int c = 0; c < 3; ++c) {
            int x = tid + (c << 8);
            if (x < WIDTH) {
#pragma unroll
                for (int k = 0; k < 2; ++k) {
                    float nx = cP[c][k], ny = cT[c][k];
                    float ox = oP[c][k], oy = oT[c][k];
                    S[c][0] += nx - ox;
                    S[c][1] += ny - oy;
                    S[c][2] += nx*nx + ny*ny - ox*ox - oy*oy;
                    S[c][3] += nx*ny - ox*oy;
                    cs[k][x + 5] = make_float4(S[c][0], S[c][1], S[c][2], S[c][3]);
                }
            }
        }
        __syncthreads();

        // ---- Phase B: 4 waves = 2 rows x 2 halves; 5 px/lane; b128 reads,
        //      lane stride 20 dwords -> minimum bank aliasing
        {
            const int r    = tid >> 6;
            const int lane = tid & 63;
            const int k    = r & 1;
            const int base = ((r >> 1) * 320) + lane * 5;   // slots [base, base+14]

            float4 w[4];
            float4 B = make_float4(0.f, 0.f, 0.f, 0.f);
#pragma unroll
            for (int j = 0; j <= 10; ++j) {
                float4 v = cs[k][base + j];
                if (j < 4) w[j] = v;
                B.x += v.x; B.y += v.y; B.z += v.z; B.w += v.w;
            }
#pragma unroll
            for (int i = 0; i < 5; ++i) {
                if (i > 0) {
                    float4 n = cs[k][base + 10 + i];
                    B.x += n.x - w[i-1].x;
                    B.y += n.y - w[i-1].y;
                    B.z += n.z - w[i-1].z;
                    B.w += n.w - w[i-1].w;
                }
                float mp  = B.x * inv121, mt = B.y * inv121;
                float mpp = mp*mp, mtt = mt*mt, mpt = mp*mt;
                float s2  = B.z * inv121 - mpp - mtt;   // sigma_p + sigma_t
                float spt = B.w * inv121 - mpt;         // sigma_pt
                float num = (2.f*mpt + SSIM_C1) * (2.f*spt + SSIM_C2);
                float den = (mpp + mtt + SSIM_C1) * (s2 + SSIM_C2);
                acc += num * __builtin_amdgcn_rcpf(den);
            }
        }
        __syncthreads();
    }

    // ---- block reduction -> one plain store per block (no atomics)
#pragma unroll
    for (int off = 32; off >= 1; off >>= 1)
        acc += __shfl_down(acc, off);
    if ((tid & 63) == 0) red[tid >> 6] = acc;
    __syncthreads();
    if (tid == 0)
        ws[blockIdx.x] = red[0] + red[1] + red[2] + red[3];
}

__global__ void ssim_reduce(const float* __restrict__ ws, float* __restrict__ out)
{
    __shared__ float red[4];
    const int tid = threadIdx.x;
    float s = 0.f;
#pragma unroll
    for (int i = 0; i < 6; ++i) s += ws[tid + (i << 8)];
#pragma unroll
    for (int off = 32; off >= 1; off >>= 1)
        s += __shfl_down(s, off);
    if ((tid & 63) == 0) red[tid >> 6] = s;
    __syncthreads();
    if (tid == 0)
        out[0] = 1.0f - (red[0] + red[1] + red[2] + red[3]) * INV_N;
}

extern "C" void kernel_launch(void* const* d_in, const int* in_sizes, int n_in,
                              void* d_out, int out_size, void* d_ws, size_t ws_size,
                              hipStream_t stream) {
    const float* pred = (const float*)d_in[0];
    const float* targ = (const float*)d_in[1];
    float* out = (float*)d_out;
    float* ws  = (float*)d_ws;          // 1536 floats of partial sums
    ssim_main<<<NBLK, 256, 0, stream>>>(pred, targ, ws);
    ssim_reduce<<<1, 256, 0, stream>>>(ws, out);
}